// Round 1
// baseline (254.645 us; speedup 1.0000x reference)
//
#include <hip/hip_runtime.h>
#include <stdint.h>

#define TT 12
#define NN 325
#define HH 64
#define EE 32
#define LHH 128
#define OO 12
#define CIN 97
#define MOFF 65
#define BB 64

typedef __attribute__((ext_vector_type(8))) short bf8;
typedef __attribute__((ext_vector_type(4))) float f4;

__device__ __forceinline__ float sigf(float x) {
  return __builtin_amdgcn_rcpf(1.f + __builtin_amdgcn_exp2f(-1.4426950408889634f * x));
}
__device__ __forceinline__ float tanhfast(float x) {
  // tanh(x) = 1 - 2/(1+e^{2x});  e^{2x} = 2^{2x*log2e}
  return 1.f - 2.f * __builtin_amdgcn_rcpf(1.f + __builtin_amdgcn_exp2f(2.8853900817779268f * x));
}
__device__ __forceinline__ unsigned short f2bf(float f) {  // RNE float->bf16
  unsigned int u = __float_as_uint(f);
  u += 0x7fffu + ((u >> 16) & 1u);
  return (unsigned short)(u >> 16);
}

// ---------------------------------------------------------------------------
// Kernel 1: meta = mean_t x[b,t,0,65:], 3 MLP hiddens, Wx / bias-gate outputs.
// grid 64 (one per batch), 256 threads.
// ---------------------------------------------------------------------------
__global__ __launch_bounds__(256) void k_meta(
    const float* __restrict__ x,
    const float* __restrict__ xw1, const float* __restrict__ xb1,
    const float* __restrict__ xw2, const float* __restrict__ xb2,
    const float* __restrict__ hw1, const float* __restrict__ hb1,
    const float* __restrict__ bw1, const float* __restrict__ bb1,
    const float* __restrict__ bw2, const float* __restrict__ bb2,
    float* __restrict__ hid_ws, float* __restrict__ wx_ws,
    float* __restrict__ bg_ws)
{
  const int b = blockIdx.x, tid = threadIdx.x;
  __shared__ float meta_s[EE];
  __shared__ float hidx_s[512], hidb_s[512];

  if (tid < EE) {
    float s = 0.f;
    #pragma unroll
    for (int t = 0; t < TT; ++t)
      s += x[(size_t)((b * TT + t) * NN) * CIN + MOFF + tid];
    meta_s[tid] = s * (1.f / 12.f);
  }
  __syncthreads();

  // hiddens: 3 MLPs x 4 gates x 128
  for (int idx = tid; idx < 1536; idx += 256) {
    const int mlp = idx >> 9, rem = idx & 511;
    const int g = rem >> 7, l = rem & 127;
    const float* W1 = (mlp == 0) ? xw1 : ((mlp == 1) ? hw1 : bw1);
    const float* B1 = (mlp == 0) ? xb1 : ((mlp == 1) ? hb1 : bb1);
    float a = B1[rem];
    const float* w = W1 + g * (EE * LHH) + l;
    #pragma unroll
    for (int e = 0; e < EE; ++e) a = fmaf(meta_s[e], w[e * LHH], a);
    a = fmaxf(a, 0.f);
    if (mlp == 0) hidx_s[rem] = a;
    else if (mlp == 2) hidb_s[rem] = a;
    else hid_ws[g * (BB * LHH) + b * LHH + l] = a;  // lwh hidden -> ws for GEMM
  }
  __syncthreads();

  // Wx and gate-bias outputs (per (g,h)): 128-dot each
  {
    const int g = tid >> 6;
    const int h = tid & 63;
    float ax = xb2[tid];  // (4,64) flat == g*64+h == tid
    float ab = bb2[tid];
    const float* wxp = xw2 + (size_t)g * (LHH * HH) + h;
    const float* wbp = bw2 + (size_t)g * (LHH * HH) + h;
    const float* hx = hidx_s + g * LHH;
    const float* hb = hidb_s + g * LHH;
    #pragma unroll 8
    for (int l = 0; l < LHH; ++l) {
      ax = fmaf(hx[l], wxp[l * HH], ax);
      ab = fmaf(hb[l], wbp[l * HH], ab);
    }
    wx_ws[b * 256 + tid] = ax;
    bg_ws[b * 256 + tid] = ab;
  }
}

// ---------------------------------------------------------------------------
// Kernel 2: Wh GEMM per gate: hid(64b x 128) @ W2(128 x 4096) -> bf16 weights
// stored in exact MFMA B-fragment order; also gathers x signal into xg.
// grid 256: g = bi>>6, i (= contraction row of Wh, 0..63) = bi&63.
// ---------------------------------------------------------------------------
__global__ __launch_bounds__(256) void k_wh(
    const float* __restrict__ x,
    const float* __restrict__ hw2, const float* __restrict__ hb2,
    const float* __restrict__ hid_ws, unsigned short* __restrict__ whb,
    float* __restrict__ xg)
{
  const int g = blockIdx.x >> 6, i = blockIdx.x & 63, tid = threadIdx.x;
  __shared__ float hs[BB][132];       // hid[b][l], padded
  __shared__ float w2s[LHH][HH];      // W2 slice [l][j] for cols i*64..i*64+63

  // x-signal gather (parallel across the 256 blocks)
  {
    const int base = blockIdx.x * 976;
    #pragma unroll
    for (int kk = 0; kk < 4; ++kk) {
      const int flat = base + kk * 256 + tid;
      if (flat < BB * TT * NN) {
        const int b = flat / (TT * NN);
        const int r = flat - b * (TT * NN);
        const int t = r / NN;
        const int n = r - t * NN;
        xg[flat] = x[(size_t)((b * TT + t) * NN + n) * CIN];
      }
    }
  }

  for (int idx = tid; idx < BB * LHH; idx += 256)
    hs[idx >> 7][idx & 127] = hid_ws[g * (BB * LHH) + idx];
  for (int idx = tid; idx < LHH * HH; idx += 256)
    w2s[idx >> 6][idx & 63] = hw2[(size_t)(g * LHH + (idx >> 6)) * 4096 + i * 64 + (idx & 63)];
  __syncthreads();

  const int rg = tid >> 4, cg = tid & 15;
  const int b0 = rg * 4, j0 = cg * 4;
  float acc[4][4] = {};
  for (int l = 0; l < LHH; l += 4) {
    f4 hv[4];
    #pragma unroll
    for (int rr = 0; rr < 4; ++rr) hv[rr] = *(const f4*)&hs[b0 + rr][l];
    #pragma unroll
    for (int ll = 0; ll < 4; ++ll) {
      const f4 wv = *(const f4*)&w2s[l + ll][j0];
      #pragma unroll
      for (int rr = 0; rr < 4; ++rr)
        #pragma unroll
        for (int jj = 0; jj < 4; ++jj)
          acc[rr][jj] = fmaf(hv[rr][ll], wv[jj], acc[rr][jj]);
    }
  }

  // store bf16 in MFMA B-frag order: element j of lane (quad*16+c16) of frag (kh,nt)
  const int kh = i >> 5, quad = (i >> 3) & 3, j8 = i & 7;
  #pragma unroll
  for (int rr = 0; rr < 4; ++rr) {
    const int b = b0 + rr;
    #pragma unroll
    for (int jj = 0; jj < 4; ++jj) {
      const int j = j0 + jj;
      const float v = acc[rr][jj] + hb2[g * 4096 + i * 64 + j];
      const int col = g * 64 + j;
      const int nt = col >> 4, c16 = col & 15;
      const int lane = quad * 16 + c16;
      whb[(size_t)((b * 32 + kh * 16 + nt) * 64 + lane) * 8 + j8] = f2bf(v);
    }
  }
}

// ---------------------------------------------------------------------------
// Kernel 3: the LSTM + head. grid (6 row-blocks, 64 batches), 256 thr = 4 waves.
// Each wave owns 16 rows for all 12 timesteps (no barriers in the T loop):
// Z(16x256) = H(16x64,bf16) @ Wh(64x256,bf16 resident in 128 VGPRs).
// C-layout puts all 4 gates of a cell in one lane -> in-register nonlinearity.
// ---------------------------------------------------------------------------
__global__ __launch_bounds__(256, 2) void k_lstm(
    const float* __restrict__ xg, const float* __restrict__ wx_ws,
    const float* __restrict__ bg_ws, const unsigned short* __restrict__ whb,
    const float* __restrict__ fc1W, const float* __restrict__ fc1b,
    const float* __restrict__ fc2W, const float* __restrict__ fc2b,
    float* __restrict__ out)
{
  const int rb = blockIdx.x, b = blockIdx.y, tid = threadIdx.x;
  const int wave = tid >> 6, lane = tid & 63, quad = lane >> 4, c16 = lane & 15;
  const int n0 = rb * 64;

  __shared__ __align__(16) unsigned short Hs[4][16][72];  // h bf16, row stride 144B (16B-aligned)
  __shared__ float Xs[TT][64];
  __shared__ float fc1s[HH * 32];
  __shared__ float fc2s[32 * OO];
  __shared__ __align__(16) float HIDf[4][16][36];
  __shared__ float fc1bs[32];
  __shared__ float fc2bs[OO];

  // stage x values for this block's 64 rows, all 12 steps
  for (int idx = tid; idx < TT * 64; idx += 256) {
    const int t = idx >> 6, r = idx & 63, n = n0 + r;
    Xs[t][r] = (n < NN) ? xg[b * (TT * NN) + t * NN + n] : 0.f;
  }
  for (int idx = tid; idx < HH * 32; idx += 256) fc1s[idx] = fc1W[idx];
  for (int idx = tid; idx < 32 * OO; idx += 256) fc2s[idx] = fc2W[idx];
  if (tid < 32) fc1bs[tid] = fc1b[tid];
  if (tid < OO) fc2bs[tid] = fc2b[tid];

  // per-lane x-weight / bias (col = nt*16 + c16), constant over t
  float wxv[16], bgv[16];
  #pragma unroll
  for (int nt = 0; nt < 16; ++nt) {
    wxv[nt] = wx_ws[b * 256 + nt * 16 + c16];
    bgv[nt] = bg_ws[b * 256 + nt * 16 + c16];
  }
  // resident Wh B-fragments: one coalesced 16B load per frag
  bf8 wf[2][16];
  #pragma unroll
  for (int kh = 0; kh < 2; ++kh)
    #pragma unroll
    for (int nt = 0; nt < 16; ++nt)
      wf[kh][nt] = *(const bf8*)(whb + (size_t)((b * 32 + kh * 16 + nt) * 64 + lane) * 8);

  float cst[16];
  #pragma unroll
  for (int q = 0; q < 16; ++q) cst[q] = 0.f;

  __syncthreads();  // Xs / fc staging visible; T-loop below is barrier-free

  #pragma unroll 1
  for (int t = 0; t < TT; ++t) {
    float xr[4];
    #pragma unroll
    for (int r = 0; r < 4; ++r) xr[r] = Xs[t][wave * 16 + quad * 4 + r];

    bf8 af0, af1;
    if (t > 0) {  // h == 0 at t==0: skip the matmul entirely
      af0 = *(const bf8*)&Hs[wave][c16][quad * 8];
      af1 = *(const bf8*)&Hs[wave][c16][32 + quad * 8];
    }

    #pragma unroll
    for (int hc = 0; hc < 4; ++hc) {
      f4 a0, a1, a2, a3;
      #pragma unroll
      for (int r = 0; r < 4; ++r) {
        a0[r] = fmaf(xr[r], wxv[hc],      bgv[hc]);
        a1[r] = fmaf(xr[r], wxv[4 + hc],  bgv[4 + hc]);
        a2[r] = fmaf(xr[r], wxv[8 + hc],  bgv[8 + hc]);
        a3[r] = fmaf(xr[r], wxv[12 + hc], bgv[12 + hc]);
      }
      if (t > 0) {
        a0 = __builtin_amdgcn_mfma_f32_16x16x32_bf16(af0, wf[0][hc],      a0, 0, 0, 0);
        a0 = __builtin_amdgcn_mfma_f32_16x16x32_bf16(af1, wf[1][hc],      a0, 0, 0, 0);
        a1 = __builtin_amdgcn_mfma_f32_16x16x32_bf16(af0, wf[0][4 + hc],  a1, 0, 0, 0);
        a1 = __builtin_amdgcn_mfma_f32_16x16x32_bf16(af1, wf[1][4 + hc],  a1, 0, 0, 0);
        a2 = __builtin_amdgcn_mfma_f32_16x16x32_bf16(af0, wf[0][8 + hc],  a2, 0, 0, 0);
        a2 = __builtin_amdgcn_mfma_f32_16x16x32_bf16(af1, wf[1][8 + hc],  a2, 0, 0, 0);
        a3 = __builtin_amdgcn_mfma_f32_16x16x32_bf16(af0, wf[0][12 + hc], a3, 0, 0, 0);
        a3 = __builtin_amdgcn_mfma_f32_16x16x32_bf16(af1, wf[1][12 + hc], a3, 0, 0, 0);
      }
      #pragma unroll
      for (int r = 0; r < 4; ++r) {
        const float gg = tanhfast(a0[r]);
        const float ii = sigf(a1[r]);
        const float ff = sigf(a2[r]);
        const float oo = sigf(a3[r]);
        const float cc = fmaf(gg, ii, cst[hc * 4 + r] * ff);
        cst[hc * 4 + r] = cc;
        const float hh = tanhfast(cc) * oo;
        Hs[wave][quad * 4 + r][hc * 16 + c16] = f2bf(hh);
      }
    }
  }

  // ---- head, fp32 (precision headroom), wave-local ----
  // hid[row][u] = relu( relu(h[row]) @ fc1 + b1 );  lane: row=c16, u=quad*8+uu
  {
    const int row = c16;
    float hrow[HH];
    #pragma unroll
    for (int kc = 0; kc < 8; ++kc) {
      const bf8 hv = *(const bf8*)&Hs[wave][row][kc * 8];
      #pragma unroll
      for (int j = 0; j < 8; ++j) {
        const unsigned int us = (unsigned short)hv[j];
        hrow[kc * 8 + j] = fmaxf(__uint_as_float(us << 16), 0.f);  // relu(h)
      }
    }
    float hid[8];
    #pragma unroll
    for (int uu = 0; uu < 8; ++uu) hid[uu] = fc1bs[quad * 8 + uu];
    #pragma unroll
    for (int k = 0; k < HH; ++k) {
      const float* wp = &fc1s[k * 32 + quad * 8];
      const f4 w0 = *(const f4*)wp;
      const f4 w1 = *(const f4*)(wp + 4);
      const float hk = hrow[k];
      hid[0] = fmaf(hk, w0[0], hid[0]);
      hid[1] = fmaf(hk, w0[1], hid[1]);
      hid[2] = fmaf(hk, w0[2], hid[2]);
      hid[3] = fmaf(hk, w0[3], hid[3]);
      hid[4] = fmaf(hk, w1[0], hid[4]);
      hid[5] = fmaf(hk, w1[1], hid[5]);
      hid[6] = fmaf(hk, w1[2], hid[6]);
      hid[7] = fmaf(hk, w1[3], hid[7]);
    }
    #pragma unroll
    for (int uu = 0; uu < 8; ++uu)
      HIDf[wave][row][quad * 8 + uu] = fmaxf(hid[uu], 0.f);
  }
  // out[row][o] = hid[row] @ fc2 + b2;  lane: row=c16, o=quad*3+oo
  {
    const int row = c16;
    float o0 = fc2bs[quad * 3 + 0];
    float o1 = fc2bs[quad * 3 + 1];
    float o2 = fc2bs[quad * 3 + 2];
    #pragma unroll
    for (int k = 0; k < 32; ++k) {
      const float hvk = HIDf[wave][row][k];
      o0 = fmaf(hvk, fc2s[k * OO + quad * 3 + 0], o0);
      o1 = fmaf(hvk, fc2s[k * OO + quad * 3 + 1], o1);
      o2 = fmaf(hvk, fc2s[k * OO + quad * 3 + 2], o2);
    }
    const int n = n0 + wave * 16 + row;
    if (n < NN) {
      out[b * (OO * NN) + (quad * 3 + 0) * NN + n] = o0;
      out[b * (OO * NN) + (quad * 3 + 1) * NN + n] = o1;
      out[b * (OO * NN) + (quad * 3 + 2) * NN + n] = o2;
    }
  }
}

// ---------------------------------------------------------------------------
extern "C" void kernel_launch(void* const* d_in, const int* in_sizes, int n_in,
                              void* d_out, int out_size, void* d_ws, size_t ws_size,
                              hipStream_t stream) {
  const float* x    = (const float*)d_in[0];
  const float* xw1  = (const float*)d_in[1];
  const float* xb1  = (const float*)d_in[2];
  const float* xw2  = (const float*)d_in[3];
  const float* xb2  = (const float*)d_in[4];
  const float* hw1  = (const float*)d_in[5];
  const float* hb1  = (const float*)d_in[6];
  const float* hw2  = (const float*)d_in[7];
  const float* hb2  = (const float*)d_in[8];
  const float* bw1  = (const float*)d_in[9];
  const float* bb1  = (const float*)d_in[10];
  const float* bw2  = (const float*)d_in[11];
  const float* bb2  = (const float*)d_in[12];
  const float* fc1W = (const float*)d_in[13];
  const float* fc1b = (const float*)d_in[14];
  const float* fc2W = (const float*)d_in[15];
  const float* fc2b = (const float*)d_in[16];
  float* out = (float*)d_out;

  float* ws = (float*)d_ws;
  float* hid_ws = ws;                        // [4][64][128]      = 32768 floats
  float* wx_ws  = ws + 32768;                // [64][256]         = 16384
  float* bg_ws  = ws + 49152;                // [64][256]         = 16384
  float* xg_ws  = ws + 65536;                // [64][12][325]     = 249600
  unsigned short* whb = (unsigned short*)(ws + 65536 + BB * TT * NN);  // 1048576 u16

  k_meta<<<64, 256, 0, stream>>>(x, xw1, xb1, xw2, xb2, hw1, hb1, bw1, bb1,
                                 bw2, bb2, hid_ws, wx_ws, bg_ws);
  k_wh<<<256, 256, 0, stream>>>(x, hw2, hb2, hid_ws, whb, xg_ws);
  k_lstm<<<dim3(6, 64), 256, 0, stream>>>(xg_ws, wx_ws, bg_ws, whb,
                                          fc1W, fc1b, fc2W, fc2b, out);
}

// Round 2
// 224.906 us; speedup vs baseline: 1.1322x; 1.1322x over previous
//
#include <hip/hip_runtime.h>
#include <stdint.h>

#define TT 12
#define NN 325
#define HH 64
#define EE 32
#define LHH 128
#define OO 12
#define CIN 97
#define MOFF 65
#define BB 64

typedef __attribute__((ext_vector_type(8))) short bf8;
typedef __attribute__((ext_vector_type(4))) float f4;

__device__ __forceinline__ float sigf(float x) {
  return __builtin_amdgcn_rcpf(1.f + __builtin_amdgcn_exp2f(-1.4426950408889634f * x));
}
__device__ __forceinline__ float tanhfast(float x) {
  // tanh(x) = 1 - 2/(1+e^{2x});  e^{2x} = 2^{2x*log2e}
  return 1.f - 2.f * __builtin_amdgcn_rcpf(1.f + __builtin_amdgcn_exp2f(2.8853900817779268f * x));
}
__device__ __forceinline__ unsigned short f2bf(float f) {  // RNE float->bf16
  unsigned int u = __float_as_uint(f);
  u += 0x7fffu + ((u >> 16) & 1u);
  return (unsigned short)(u >> 16);
}
__device__ __forceinline__ float bf2f(unsigned short s) {
  return __uint_as_float(((unsigned int)s) << 16);
}

// ---------------------------------------------------------------------------
// Kernel 1: meta = mean_t x[b,t,0,65:], 3 MLP hiddens, Wx / bias-gate outputs.
// grid 64 (one per batch), 256 threads.
// ---------------------------------------------------------------------------
__global__ __launch_bounds__(256) void k_meta(
    const float* __restrict__ x,
    const float* __restrict__ xw1, const float* __restrict__ xb1,
    const float* __restrict__ xw2, const float* __restrict__ xb2,
    const float* __restrict__ hw1, const float* __restrict__ hb1,
    const float* __restrict__ bw1, const float* __restrict__ bb1,
    const float* __restrict__ bw2, const float* __restrict__ bb2,
    float* __restrict__ hid_ws, float* __restrict__ wx_ws,
    float* __restrict__ bg_ws)
{
  const int b = blockIdx.x, tid = threadIdx.x;
  __shared__ float meta_s[EE];
  __shared__ float hidx_s[512], hidb_s[512];

  if (tid < EE) {
    float s = 0.f;
    #pragma unroll
    for (int t = 0; t < TT; ++t)
      s += x[(size_t)((b * TT + t) * NN) * CIN + MOFF + tid];
    meta_s[tid] = s * (1.f / 12.f);
  }
  __syncthreads();

  // hiddens: 3 MLPs x 4 gates x 128
  for (int idx = tid; idx < 1536; idx += 256) {
    const int mlp = idx >> 9, rem = idx & 511;
    const int g = rem >> 7, l = rem & 127;
    const float* W1 = (mlp == 0) ? xw1 : ((mlp == 1) ? hw1 : bw1);
    const float* B1 = (mlp == 0) ? xb1 : ((mlp == 1) ? hb1 : bb1);
    float a = B1[rem];
    const float* w = W1 + g * (EE * LHH) + l;
    #pragma unroll
    for (int e = 0; e < EE; ++e) a = fmaf(meta_s[e], w[e * LHH], a);
    a = fmaxf(a, 0.f);
    if (mlp == 0) hidx_s[rem] = a;
    else if (mlp == 2) hidb_s[rem] = a;
    else hid_ws[g * (BB * LHH) + b * LHH + l] = a;  // lwh hidden -> ws for GEMM
  }
  __syncthreads();

  // Wx and gate-bias outputs (per (g,h)): 128-dot each
  {
    const int g = tid >> 6;
    const int h = tid & 63;
    float ax = xb2[tid];  // (4,64) flat == g*64+h == tid
    float ab = bb2[tid];
    const float* wxp = xw2 + (size_t)g * (LHH * HH) + h;
    const float* wbp = bw2 + (size_t)g * (LHH * HH) + h;
    const float* hx = hidx_s + g * LHH;
    const float* hb = hidb_s + g * LHH;
    #pragma unroll 8
    for (int l = 0; l < LHH; ++l) {
      ax = fmaf(hx[l], wxp[l * HH], ax);
      ab = fmaf(hb[l], wbp[l * HH], ab);
    }
    wx_ws[b * 256 + tid] = ax;
    bg_ws[b * 256 + tid] = ab;
  }
}

// ---------------------------------------------------------------------------
// Kernel 2: Wh GEMM per gate: hid(64b x 128) @ W2(128 x 4096) -> bf16 weights
// stored in exact MFMA B-fragment order; also gathers x signal into xg.
// grid 256: g = bi>>6, i (= contraction row of Wh, 0..63) = bi&63.
// ---------------------------------------------------------------------------
__global__ __launch_bounds__(256) void k_wh(
    const float* __restrict__ x,
    const float* __restrict__ hw2, const float* __restrict__ hb2,
    const float* __restrict__ hid_ws, unsigned short* __restrict__ whb,
    float* __restrict__ xg)
{
  const int g = blockIdx.x >> 6, i = blockIdx.x & 63, tid = threadIdx.x;
  __shared__ float hs[BB][132];       // hid[b][l], padded
  __shared__ float w2s[LHH][HH];      // W2 slice [l][j] for cols i*64..i*64+63

  // x-signal gather (parallel across the 256 blocks)
  {
    const int base = blockIdx.x * 976;
    #pragma unroll
    for (int kk = 0; kk < 4; ++kk) {
      const int flat = base + kk * 256 + tid;
      if (flat < BB * TT * NN) {
        const int b = flat / (TT * NN);
        const int r = flat - b * (TT * NN);
        const int t = r / NN;
        const int n = r - t * NN;
        xg[flat] = x[(size_t)((b * TT + t) * NN + n) * CIN];
      }
    }
  }

  for (int idx = tid; idx < BB * LHH; idx += 256)
    hs[idx >> 7][idx & 127] = hid_ws[g * (BB * LHH) + idx];
  for (int idx = tid; idx < LHH * HH; idx += 256)
    w2s[idx >> 6][idx & 63] = hw2[(size_t)(g * LHH + (idx >> 6)) * 4096 + i * 64 + (idx & 63)];
  __syncthreads();

  const int rg = tid >> 4, cg = tid & 15;
  const int b0 = rg * 4, j0 = cg * 4;
  float acc[4][4] = {};
  for (int l = 0; l < LHH; l += 4) {
    f4 hv[4];
    #pragma unroll
    for (int rr = 0; rr < 4; ++rr) hv[rr] = *(const f4*)&hs[b0 + rr][l];
    #pragma unroll
    for (int ll = 0; ll < 4; ++ll) {
      const f4 wv = *(const f4*)&w2s[l + ll][j0];
      #pragma unroll
      for (int rr = 0; rr < 4; ++rr)
        #pragma unroll
        for (int jj = 0; jj < 4; ++jj)
          acc[rr][jj] = fmaf(hv[rr][ll], wv[jj], acc[rr][jj]);
    }
  }

  // store bf16 in MFMA B-frag order: element j of lane (quad*16+c16) of frag (kh,nt)
  const int kh = i >> 5, quad = (i >> 3) & 3, j8 = i & 7;
  #pragma unroll
  for (int rr = 0; rr < 4; ++rr) {
    const int b = b0 + rr;
    #pragma unroll
    for (int jj = 0; jj < 4; ++jj) {
      const int j = j0 + jj;
      const float v = acc[rr][jj] + hb2[g * 4096 + i * 64 + j];
      const int col = g * 64 + j;
      const int nt = col >> 4, c16 = col & 15;
      const int lane = quad * 16 + c16;
      whb[(size_t)((b * 32 + kh * 16 + nt) * 64 + lane) * 8 + j8] = f2bf(v);
    }
  }
}

// ---------------------------------------------------------------------------
// Kernel 3: LSTM + head. grid (21 row-tiles, 64 batches), 256 thr = 4 waves.
// Block owns 16 rows; wave w computes ALL 4 gates for h-cols [w*16,w*16+16):
//   8 MFMAs/step/wave, 20 trans/lane/step. The 16x64 h tile round-trips
//   through double-buffered LDS with one barrier per step. 1344 blocks
//   (~5 waves/SIMD) vs R1's 1.5 -> latency now hidden by TLP.
// ---------------------------------------------------------------------------
__global__ __launch_bounds__(256, 4) void k_lstm(
    const float* __restrict__ xg, const float* __restrict__ wx_ws,
    const float* __restrict__ bg_ws, const unsigned short* __restrict__ whb,
    const float* __restrict__ fc1W, const float* __restrict__ fc1b,
    const float* __restrict__ fc2W, const float* __restrict__ fc2b,
    float* __restrict__ out)
{
  const int rb = blockIdx.x, b = blockIdx.y, tid = threadIdx.x;
  const int wave = tid >> 6, lane = tid & 63, quad = lane >> 4, c16 = lane & 15;
  const int n0 = rb * 16;

  __shared__ __align__(16) unsigned short Hs[2][16][72];  // h bf16, dbuf, row stride 144B
  __shared__ float Xs[TT][16];
  __shared__ float fc1s[HH * 32];
  __shared__ float fc2s[32 * OO];
  __shared__ float HIDs[16][34];
  __shared__ float fc1bs[32];
  __shared__ float fc2bs[OO];

  // stage x for this block's 16 rows, all 12 steps
  for (int idx = tid; idx < TT * 16; idx += 256) {
    const int t = idx >> 4, r = idx & 15, n = n0 + r;
    Xs[t][r] = (n < NN) ? xg[b * (TT * NN) + t * NN + n] : 0.f;
  }
  for (int idx = tid; idx < HH * 32; idx += 256) fc1s[idx] = fc1W[idx];
  for (int idx = tid; idx < 32 * OO; idx += 256) fc2s[idx] = fc2W[idx];
  if (tid < 32) fc1bs[tid] = fc1b[tid];
  if (tid < OO) fc2bs[tid] = fc2b[tid];

  // per-lane x-weight / bias for this wave's 4 gate-columns (col = g*64 + wave*16 + c16)
  float wxv[4], bgv[4];
  #pragma unroll
  for (int g = 0; g < 4; ++g) {
    wxv[g] = wx_ws[b * 256 + g * 64 + wave * 16 + c16];
    bgv[g] = bg_ws[b * 256 + g * 64 + wave * 16 + c16];
  }
  // resident Wh B-fragments for this wave's columns: nt = g*4 + wave
  bf8 wf[2][4];
  #pragma unroll
  for (int kh = 0; kh < 2; ++kh)
    #pragma unroll
    for (int g = 0; g < 4; ++g)
      wf[kh][g] = *(const bf8*)(whb + (size_t)((b * 32 + kh * 16 + g * 4 + wave) * 64 + lane) * 8);

  float cst[4];
  #pragma unroll
  for (int r = 0; r < 4; ++r) cst[r] = 0.f;

  __syncthreads();  // Xs / fc staging visible

  #pragma unroll 1
  for (int t = 0; t < TT; ++t) {
    float xr[4];
    #pragma unroll
    for (int r = 0; r < 4; ++r) xr[r] = Xs[t][quad * 4 + r];

    bf8 af0, af1;
    if (t > 0) {  // A-frag: full 16x64 h of this block (shared across waves)
      af0 = *(const bf8*)&Hs[(t - 1) & 1][c16][quad * 8];
      af1 = *(const bf8*)&Hs[(t - 1) & 1][c16][32 + quad * 8];
    }

    f4 a0, a1, a2, a3;
    #pragma unroll
    for (int r = 0; r < 4; ++r) {
      a0[r] = fmaf(xr[r], wxv[0], bgv[0]);
      a1[r] = fmaf(xr[r], wxv[1], bgv[1]);
      a2[r] = fmaf(xr[r], wxv[2], bgv[2]);
      a3[r] = fmaf(xr[r], wxv[3], bgv[3]);
    }
    if (t > 0) {
      a0 = __builtin_amdgcn_mfma_f32_16x16x32_bf16(af0, wf[0][0], a0, 0, 0, 0);
      a0 = __builtin_amdgcn_mfma_f32_16x16x32_bf16(af1, wf[1][0], a0, 0, 0, 0);
      a1 = __builtin_amdgcn_mfma_f32_16x16x32_bf16(af0, wf[0][1], a1, 0, 0, 0);
      a1 = __builtin_amdgcn_mfma_f32_16x16x32_bf16(af1, wf[1][1], a1, 0, 0, 0);
      a2 = __builtin_amdgcn_mfma_f32_16x16x32_bf16(af0, wf[0][2], a2, 0, 0, 0);
      a2 = __builtin_amdgcn_mfma_f32_16x16x32_bf16(af1, wf[1][2], a2, 0, 0, 0);
      a3 = __builtin_amdgcn_mfma_f32_16x16x32_bf16(af0, wf[0][3], a3, 0, 0, 0);
      a3 = __builtin_amdgcn_mfma_f32_16x16x32_bf16(af1, wf[1][3], a3, 0, 0, 0);
    }
    #pragma unroll
    for (int r = 0; r < 4; ++r) {
      const float gg = tanhfast(a0[r]);
      const float ii = sigf(a1[r]);
      const float ff = sigf(a2[r]);
      const float oo = sigf(a3[r]);
      const float cc = fmaf(gg, ii, cst[r] * ff);
      cst[r] = cc;
      const float hh = tanhfast(cc) * oo;
      Hs[t & 1][quad * 4 + r][wave * 16 + c16] = f2bf(hh);
    }
    __syncthreads();
  }

  // ---- head, fp32. final h is in Hs[(TT-1)&1] == Hs[1]. ----
  // Step A: hid[16][32]: thread (row = tid&15, uu = tid>>4) computes u = 2uu, 2uu+1
  {
    const int row = tid & 15, uu = tid >> 4;
    float h0 = fc1bs[2 * uu], h1 = fc1bs[2 * uu + 1];
    #pragma unroll
    for (int kc = 0; kc < 8; ++kc) {
      const bf8 hv = *(const bf8*)&Hs[1][row][kc * 8];
      #pragma unroll
      for (int j = 0; j < 8; ++j) {
        const float hk = fmaxf(bf2f((unsigned short)hv[j]), 0.f);  // relu(h)
        const int k = kc * 8 + j;
        h0 = fmaf(hk, fc1s[k * 32 + 2 * uu], h0);
        h1 = fmaf(hk, fc1s[k * 32 + 2 * uu + 1], h1);
      }
    }
    HIDs[row][2 * uu] = fmaxf(h0, 0.f);
    HIDs[row][2 * uu + 1] = fmaxf(h1, 0.f);
  }
  __syncthreads();
  // Step B: out[row][o] = hid[row] @ fc2 + b2; threads 0..191: o = tid>>4, row = tid&15
  if (tid < 16 * OO) {
    const int o = tid >> 4, row = tid & 15;
    float acc = fc2bs[o];
    #pragma unroll
    for (int k = 0; k < 32; ++k)
      acc = fmaf(HIDs[row][k], fc2s[k * OO + o], acc);
    const int n = n0 + row;
    if (n < NN)
      out[b * (OO * NN) + o * NN + n] = acc;
  }
}

// ---------------------------------------------------------------------------
extern "C" void kernel_launch(void* const* d_in, const int* in_sizes, int n_in,
                              void* d_out, int out_size, void* d_ws, size_t ws_size,
                              hipStream_t stream) {
  const float* x    = (const float*)d_in[0];
  const float* xw1  = (const float*)d_in[1];
  const float* xb1  = (const float*)d_in[2];
  const float* xw2  = (const float*)d_in[3];
  const float* xb2  = (const float*)d_in[4];
  const float* hw1  = (const float*)d_in[5];
  const float* hb1  = (const float*)d_in[6];
  const float* hw2  = (const float*)d_in[7];
  const float* hb2  = (const float*)d_in[8];
  const float* bw1  = (const float*)d_in[9];
  const float* bb1  = (const float*)d_in[10];
  const float* bw2  = (const float*)d_in[11];
  const float* bb2  = (const float*)d_in[12];
  const float* fc1W = (const float*)d_in[13];
  const float* fc1b = (const float*)d_in[14];
  const float* fc2W = (const float*)d_in[15];
  const float* fc2b = (const float*)d_in[16];
  float* out = (float*)d_out;

  float* ws = (float*)d_ws;
  float* hid_ws = ws;                        // [4][64][128]      = 32768 floats
  float* wx_ws  = ws + 32768;                // [64][256]         = 16384
  float* bg_ws  = ws + 49152;                // [64][256]         = 16384
  float* xg_ws  = ws + 65536;                // [64][12][325]     = 249600
  unsigned short* whb = (unsigned short*)(ws + 65536 + BB * TT * NN);  // 1048576 u16

  k_meta<<<64, 256, 0, stream>>>(x, xw1, xb1, xw2, xb2, hw1, hb1, bw1, bb1,
                                 bw2, bb2, hid_ws, wx_ws, bg_ws);
  k_wh<<<256, 256, 0, stream>>>(x, hw2, hb2, hid_ws, whb, xg_ws);
  k_lstm<<<dim3(21, 64), 256, 0, stream>>>(xg_ws, wx_ws, bg_ws, whb,
                                           fc1W, fc1b, fc2W, fc2b, out);
}